// Round 4
// baseline (107.391 us; speedup 1.0000x reference)
//
#include <hip/hip_runtime.h>

typedef float f2 __attribute__((ext_vector_type(2)));

#define PSTRIDE 32   // f2 entries per triangle row (256 B); 28 used + 4 pad

// ---- packed fp32 helpers (compiler scalarizes f2 math on its own, so force
// ---- VOP3P with inline asm; "s" operand = SGPR pair with equal halves) ----
static __device__ __forceinline__ f2 pk_add_sv(f2 s, f2 v) {
    f2 d; asm("v_pk_add_f32 %0, %1, %2" : "=v"(d) : "s"(s), "v"(v)); return d;
}
static __device__ __forceinline__ f2 pk_mul_sv(f2 s, f2 v) {
    f2 d; asm("v_pk_mul_f32 %0, %1, %2" : "=v"(d) : "s"(s), "v"(v)); return d;
}
static __device__ __forceinline__ f2 pk_fma_svv(f2 s, f2 b, f2 c) {
    f2 d; asm("v_pk_fma_f32 %0, %1, %2, %3" : "=v"(d) : "s"(s), "v"(b), "v"(c)); return d;
}
static __device__ __forceinline__ f2 pk_mul_vv(f2 a, f2 b) {
    f2 d; asm("v_pk_mul_f32 %0, %1, %2" : "=v"(d) : "v"(a), "v"(b)); return d;
}
static __device__ __forceinline__ f2 pk_fma_vvv(f2 a, f2 b, f2 c) {
    f2 d; asm("v_pk_fma_f32 %0, %1, %2, %3" : "=v"(d) : "v"(a), "v"(b), "v"(c)); return d;
}
// dot(a_const, v) with a in SGPR pairs
static __device__ __forceinline__ f2 dot3_s(f2 ax, f2 ay, f2 az, f2 vx, f2 vy, f2 vz) {
    return pk_fma_svv(az, vz, pk_fma_svv(ay, vy, pk_mul_sv(ax, vx)));
}
static __device__ __forceinline__ f2 dot3_v(f2 ax, f2 ay, f2 az) {
    return pk_fma_vvv(az, az, pk_fma_vvv(ay, ay, pk_mul_vv(ax, ax)));
}

// ---------------- Kernel A: per-triangle invariants (duplicated pairs) ------
__global__ __launch_bounds__(256) void tri_pre_kernel(
    const float* __restrict__ points, float* __restrict__ pre)
{
    const int t = threadIdx.x;   // one triangle per thread, 1 block of 256
    const float* tp = points + t * 9;
    float Ax = tp[0], Ay = tp[1], Az = tp[2];
    float Bx = tp[3], By = tp[4], Bz = tp[5];
    float Cx = tp[6], Cy = tp[7], Cz = tp[8];

    float acx = Ax - Cx, acy = Ay - Cy, acz = Az - Cz;
    float bax = Bx - Ax, bay = By - Ay, baz = Bz - Az;
    float cbx = Cx - Bx, cby = Cy - By, cbz = Cz - Bz;

    // nor = cross(ba, ac)
    float nx = bay * acz - baz * acy;
    float ny = baz * acx - bax * acz;
    float nz = bax * acy - bay * acx;

    // cross(ba, nor), cross(cb, nor), cross(ac, nor)
    float c1x = bay * nz - baz * ny, c1y = baz * nx - bax * nz, c1z = bax * ny - bay * nx;
    float c2x = cby * nz - cbz * ny, c2y = cbz * nx - cbx * nz, c2z = cbx * ny - cby * nx;
    float c3x = acy * nz - acz * ny, c3y = acz * nx - acx * nz, c3z = acx * ny - acy * nx;

    f2* s = ((f2*)pre) + t * PSTRIDE;
    // negated A (pa = p + nA), negated edges (pb = pa + nba, d1 = pa + nba*t1),
    // negated edge-reciprocals (t = med3(dot(nedge,pv)*ninv, 0, 1))
    s[0]  = (f2){-Ax, -Ax};  s[1]  = (f2){-Ay, -Ay};  s[2]  = (f2){-Az, -Az};
    s[3]  = (f2){-bax,-bax}; s[4]  = (f2){-bay,-bay}; s[5]  = (f2){-baz,-baz};
    s[6]  = (f2){-cbx,-cbx}; s[7]  = (f2){-cby,-cby}; s[8]  = (f2){-cbz,-cbz};
    s[9]  = (f2){-acx,-acx}; s[10] = (f2){-acy,-acy}; s[11] = (f2){-acz,-acz};
    s[12] = (f2){c1x, c1x};  s[13] = (f2){c1y, c1y};  s[14] = (f2){c1z, c1z};
    s[15] = (f2){c2x, c2x};  s[16] = (f2){c2y, c2y};  s[17] = (f2){c2z, c2z};
    s[18] = (f2){c3x, c3x};  s[19] = (f2){c3y, c3y};  s[20] = (f2){c3z, c3z};
    s[21] = (f2){nx, nx};    s[22] = (f2){ny, ny};    s[23] = (f2){nz, nz};
    float ib = -1.0f / (bax * bax + bay * bay + baz * baz);
    float ic = -1.0f / (cbx * cbx + cby * cby + cbz * cbz);
    float ia = -1.0f / (acx * acx + acy * acy + acz * acz);
    float in = 1.0f / (nx * nx + ny * ny + nz * nz);
    s[24] = (f2){ib, ib}; s[25] = (f2){ic, ic}; s[26] = (f2){ia, ia}; s[27] = (f2){in, in};
    s[28] = (f2){0,0}; s[29] = (f2){0,0}; s[30] = (f2){0,0}; s[31] = (f2){0,0};
}

// ---------------- Kernel B: main loop ---------------------------------------
// Block = 512 threads = 8 waves; block covers 128 points (2/thread, packed
// v_pk_* fp32). Wave w handles triangle chunk [w*32, w*32+32); SMEM feeds the
// wave-uniform triangle constants as SGPR pairs.
__global__ __launch_bounds__(512, 8) void tri_main_kernel(
    const float* __restrict__ p, const float* __restrict__ pre,
    float* __restrict__ out)
{
    __shared__ float red[8][128];

    const int tid  = threadIdx.x;
    const int lane = tid & 63;
    const int chunk = __builtin_amdgcn_readfirstlane(tid >> 6);  // wave id, uniform

    const int pt0 = blockIdx.x * 128 + lane;
    const int pt1 = pt0 + 64;

    f2 px = { p[3 * pt0 + 0], p[3 * pt1 + 0] };
    f2 py = { p[3 * pt0 + 1], p[3 * pt1 + 1] };
    f2 pz = { p[3 * pt0 + 2], p[3 * pt1 + 2] };

    float sum0 = 0.0f, sum1 = 0.0f;

    // exp(-32*(d-0.04)) = exp2(d * (-32*log2e) + 32*0.04*log2e)
    const float EK = -46.166241308446834f;
    const float EB = 1.8466496523378732f;

    const f2* base = ((const f2*)pre) + (chunk * 32) * PSTRIDE;

#pragma unroll 2
    for (int jj = 0; jj < 32; ++jj) {
        const f2* s = base + jj * PSTRIDE;   // uniform -> s_load, SGPR pairs

        // segment 1 (edge ba, from A)
        f2 pax = pk_add_sv(s[0], px), pay = pk_add_sv(s[1], py), paz = pk_add_sv(s[2], pz);
        f2 s1  = dot3_s(s[12], s[13], s[14], pax, pay, paz);
        f2 m1  = dot3_s(s[3], s[4], s[5], pax, pay, paz);   // -dot(ba,pa)
        f2 t1  = pk_mul_sv(s[24], m1);                      // dot(ba,pa)*inv_ba
        t1.x = __builtin_amdgcn_fmed3f(t1.x, 0.0f, 1.0f);
        t1.y = __builtin_amdgcn_fmed3f(t1.y, 0.0f, 1.0f);
        f2 d1x = pk_fma_svv(s[3], t1, pax);                 // pa - ba*t1
        f2 d1y = pk_fma_svv(s[4], t1, pay);
        f2 d1z = pk_fma_svv(s[5], t1, paz);
        f2 e1  = dot3_v(d1x, d1y, d1z);

        // segment 2 (edge cb, from B); pb = pa - ba
        f2 pbx = pk_add_sv(s[3], pax), pby = pk_add_sv(s[4], pay), pbz = pk_add_sv(s[5], paz);
        f2 s2  = dot3_s(s[15], s[16], s[17], pbx, pby, pbz);
        f2 m2  = dot3_s(s[6], s[7], s[8], pbx, pby, pbz);
        f2 t2  = pk_mul_sv(s[25], m2);
        t2.x = __builtin_amdgcn_fmed3f(t2.x, 0.0f, 1.0f);
        t2.y = __builtin_amdgcn_fmed3f(t2.y, 0.0f, 1.0f);
        f2 d2x = pk_fma_svv(s[6], t2, pbx);
        f2 d2y = pk_fma_svv(s[7], t2, pby);
        f2 d2z = pk_fma_svv(s[8], t2, pbz);
        f2 e2  = dot3_v(d2x, d2y, d2z);

        // segment 3 (edge ac, from C); pc = pb - cb
        f2 pcx = pk_add_sv(s[6], pbx), pcy = pk_add_sv(s[7], pby), pcz = pk_add_sv(s[8], pbz);
        f2 s3  = dot3_s(s[18], s[19], s[20], pcx, pcy, pcz);
        f2 m3  = dot3_s(s[9], s[10], s[11], pcx, pcy, pcz);
        f2 t3  = pk_mul_sv(s[26], m3);
        t3.x = __builtin_amdgcn_fmed3f(t3.x, 0.0f, 1.0f);
        t3.y = __builtin_amdgcn_fmed3f(t3.y, 0.0f, 1.0f);
        f2 d3x = pk_fma_svv(s[9], t3, pcx);
        f2 d3y = pk_fma_svv(s[10], t3, pcy);
        f2 d3z = pk_fma_svv(s[11], t3, pcz);
        f2 e3  = dot3_v(d3x, d3y, d3z);

        // plane distance
        f2 dn  = dot3_s(s[21], s[22], s[23], pax, pay, paz);
        f2 opp = pk_mul_sv(s[27], pk_mul_vv(dn, dn));

        // inside <=> min3(s)>=0 AND med3(s)>0  (== sign-sum >= 2)
        float mn0  = fminf(fminf(s1.x, s2.x), s3.x);
        float mn1  = fminf(fminf(s1.y, s2.y), s3.y);
        float med0 = __builtin_amdgcn_fmed3f(s1.x, s2.x, s3.x);
        float med1 = __builtin_amdgcn_fmed3f(s1.y, s2.y, s3.y);
        float same0 = fminf(fminf(e1.x, e2.x), e3.x);
        float same1 = fminf(fminf(e1.y, e2.y), e3.y);
        bool in0 = (med0 > 0.0f) & (mn0 >= 0.0f);
        bool in1 = (med1 > 0.0f) & (mn1 >= 0.0f);
        float q0 = in0 ? opp.x : same0;
        float q1 = in1 ? opp.y : same1;

        float dd0 = __builtin_amdgcn_sqrtf(fmaxf(q0, 1e-8f));
        float dd1 = __builtin_amdgcn_sqrtf(fmaxf(q1, 1e-8f));
        sum0 += __builtin_amdgcn_exp2f(fmaf(dd0, EK, EB));
        sum1 += __builtin_amdgcn_exp2f(fmaf(dd1, EK, EB));
    }

    red[chunk][lane]      = sum0;
    red[chunk][lane + 64] = sum1;
    __syncthreads();

    if (tid < 128) {
        float total = ((red[0][tid] + red[1][tid]) + (red[2][tid] + red[3][tid]))
                    + ((red[4][tid] + red[5][tid]) + (red[6][tid] + red[7][tid]));
        out[blockIdx.x * 128 + tid] =
            -__builtin_amdgcn_logf(fmaxf(total, 1e-6f)) * 0.02166084939249829f;
    }
}

extern "C" void kernel_launch(void* const* d_in, const int* in_sizes, int n_in,
                              void* d_out, int out_size, void* d_ws, size_t ws_size,
                              hipStream_t stream) {
    const float* p      = (const float*)d_in[0];
    const float* points = (const float*)d_in[1];
    float* out          = (float*)d_out;
    float* pre          = (float*)d_ws;          // 256 * 32 * 8 B = 64 KB

    hipLaunchKernelGGL(tri_pre_kernel, dim3(1), dim3(256), 0, stream, points, pre);

    const int n_pts = in_sizes[0] / 3;
    const int blocks = (n_pts + 127) / 128;      // 1024 for 131072 pts
    hipLaunchKernelGGL(tri_main_kernel, dim3(blocks), dim3(512), 0, stream,
                       p, pre, out);
}

// Round 5
// 98.831 us; speedup vs baseline: 1.0866x; 1.0866x over previous
//
#include <hip/hip_runtime.h>

typedef float f2 __attribute__((ext_vector_type(2)));

#define PSTRIDE 32   // floats per triangle row (128 B); 26 used + 6 pad

// ---- VOP3P packed fp32 with SGPR-pair constant + op_sel dword broadcast ----
// _s0: broadcast dword0 of the SGPR pair to both halves; _s1: dword1.
static __device__ __forceinline__ f2 pk_add_s0(f2 s, f2 v){f2 d; asm("v_pk_add_f32 %0, %1, %2 op_sel:[0,0] op_sel_hi:[0,1]":"=v"(d):"s"(s),"v"(v)); return d;}
static __device__ __forceinline__ f2 pk_add_s1(f2 s, f2 v){f2 d; asm("v_pk_add_f32 %0, %1, %2 op_sel:[1,0] op_sel_hi:[1,1]":"=v"(d):"s"(s),"v"(v)); return d;}
static __device__ __forceinline__ f2 pk_mul_s0(f2 s, f2 v){f2 d; asm("v_pk_mul_f32 %0, %1, %2 op_sel:[0,0] op_sel_hi:[0,1]":"=v"(d):"s"(s),"v"(v)); return d;}
static __device__ __forceinline__ f2 pk_mul_s1(f2 s, f2 v){f2 d; asm("v_pk_mul_f32 %0, %1, %2 op_sel:[1,0] op_sel_hi:[1,1]":"=v"(d):"s"(s),"v"(v)); return d;}
static __device__ __forceinline__ f2 pk_fma_s0(f2 s, f2 b, f2 c){f2 d; asm("v_pk_fma_f32 %0, %1, %2, %3 op_sel:[0,0,0] op_sel_hi:[0,1,1]":"=v"(d):"s"(s),"v"(b),"v"(c)); return d;}
static __device__ __forceinline__ f2 pk_fma_s1(f2 s, f2 b, f2 c){f2 d; asm("v_pk_fma_f32 %0, %1, %2, %3 op_sel:[1,0,0] op_sel_hi:[1,1,1]":"=v"(d):"s"(s),"v"(b),"v"(c)); return d;}
static __device__ __forceinline__ f2 pk_mul_vv(f2 a, f2 b){f2 d; asm("v_pk_mul_f32 %0, %1, %2":"=v"(d):"v"(a),"v"(b)); return d;}
static __device__ __forceinline__ f2 pk_add_vv(f2 a, f2 b){f2 d; asm("v_pk_add_f32 %0, %1, %2":"=v"(d):"v"(a),"v"(b)); return d;}
static __device__ __forceinline__ f2 pk_fma_vvv(f2 a, f2 b, f2 c){f2 d; asm("v_pk_fma_f32 %0, %1, %2, %3":"=v"(d):"v"(a),"v"(b),"v"(c)); return d;}
static __device__ __forceinline__ f2 dot3_v(f2 ax, f2 ay, f2 az){
    return pk_fma_vvv(az, az, pk_fma_vvv(ay, ay, pk_mul_vv(ax, ax)));
}

// ---------------- Kernel A: per-triangle invariants (26 floats/row) ---------
// Row layout (float idx -> value), pair Lk = floats (2k, 2k+1):
//  0:-Ax 1:-Ay | 2:-Az 3:-bax | 4:-bay 5:-baz | 6:-cbx 7:-cby | 8:-cbz 9:-acx
// 10:-acy 11:-acz | 12:c1x 13:c1y | 14:c1z 15:c2x | 16:c2y 17:c2z
// 18:nx 19:ny | 20:nz 21:ib | 22:ic 23:ia | 24:inn 25:nsq   (ib,ic,ia negated)
__global__ __launch_bounds__(256) void tri_pre_kernel(
    const float* __restrict__ points, float* __restrict__ pre)
{
    const int t = threadIdx.x;   // one triangle per thread, 1 block of 256
    const float* tp = points + t * 9;
    float Ax = tp[0], Ay = tp[1], Az = tp[2];
    float Bx = tp[3], By = tp[4], Bz = tp[5];
    float Cx = tp[6], Cy = tp[7], Cz = tp[8];

    float acx = Ax - Cx, acy = Ay - Cy, acz = Az - Cz;
    float bax = Bx - Ax, bay = By - Ay, baz = Bz - Az;
    float cbx = Cx - Bx, cby = Cy - By, cbz = Cz - Bz;

    // nor = cross(ba, ac)
    float nx = bay * acz - baz * acy;
    float ny = baz * acx - bax * acz;
    float nz = bax * acy - bay * acx;

    // c1 = cross(ba, nor), c2 = cross(cb, nor)   (c3 derived via identity)
    float c1x = bay * nz - baz * ny, c1y = baz * nx - bax * nz, c1z = bax * ny - bay * nx;
    float c2x = cby * nz - cbz * ny, c2y = cbz * nx - cbx * nz, c2z = cbx * ny - cby * nx;

    float nsq = nx * nx + ny * ny + nz * nz;

    float* r = pre + t * PSTRIDE;
    r[0]  = -Ax;  r[1]  = -Ay;  r[2]  = -Az;
    r[3]  = -bax; r[4]  = -bay; r[5]  = -baz;
    r[6]  = -cbx; r[7]  = -cby; r[8]  = -cbz;
    r[9]  = -acx; r[10] = -acy; r[11] = -acz;
    r[12] = c1x;  r[13] = c1y;  r[14] = c1z;
    r[15] = c2x;  r[16] = c2y;  r[17] = c2z;
    r[18] = nx;   r[19] = ny;   r[20] = nz;
    r[21] = -1.0f / (bax * bax + bay * bay + baz * baz);
    r[22] = -1.0f / (cbx * cbx + cby * cby + cbz * cbz);
    r[23] = -1.0f / (acx * acx + acy * acy + acz * acz);
    r[24] = 1.0f / nsq;
    r[25] = nsq;
    r[26] = 0.0f; r[27] = 0.0f; r[28] = 0.0f; r[29] = 0.0f; r[30] = 0.0f; r[31] = 0.0f;
}

// ---------------- Kernel B: main loop ---------------------------------------
// Block = 512 threads = 8 waves; block covers 128 points (2/thread, v_pk_*).
// Wave w handles triangle chunk [w*32, w*32+32); constants via s_load into
// SGPR pairs, broadcast per-instruction with op_sel.
__global__ __launch_bounds__(512, 8) void tri_main_kernel(
    const float* __restrict__ p, const float* __restrict__ pre,
    float* __restrict__ out)
{
    __shared__ float red[8][128];

    const int tid  = threadIdx.x;
    const int lane = tid & 63;
    const int chunk = __builtin_amdgcn_readfirstlane(tid >> 6);  // wave id, uniform

    const int pt0 = blockIdx.x * 128 + lane;
    const int pt1 = pt0 + 64;

    f2 px = { p[3 * pt0 + 0], p[3 * pt1 + 0] };
    f2 py = { p[3 * pt0 + 1], p[3 * pt1 + 1] };
    f2 pz = { p[3 * pt0 + 2], p[3 * pt1 + 2] };

    float sum0 = 0.0f, sum1 = 0.0f;

    // exp(-32*(d-0.04)) = exp2(d * (-32*log2e) + 32*0.04*log2e)
    const float EK = -46.166241308446834f;
    const float EB = 1.8466496523378732f;

    const f2* base = (const f2*)(pre + (chunk * 32) * PSTRIDE);

#pragma unroll 2
    for (int jj = 0; jj < 32; ++jj) {
        const f2* s = base + jj * (PSTRIDE / 2);   // uniform -> s_load pairs
        f2 L0 = s[0], L1 = s[1], L2 = s[2], L3 = s[3], L4 = s[4], L5 = s[5],
           L6 = s[6], L7 = s[7], L8 = s[8], L9 = s[9], L10 = s[10], L11 = s[11],
           L12 = s[12];

        // pa = p - A   (nA stored)
        f2 pax = pk_add_s0(L0, px);
        f2 pay = pk_add_s1(L0, py);
        f2 paz = pk_add_s0(L1, pz);

        // s1 = c1.pa
        f2 s1v = pk_fma_s0(L7, paz, pk_fma_s1(L6, pay, pk_mul_s0(L6, pax)));
        // m1 = -ba.pa ; t1 = m1*(-1/bsq) clamped
        f2 m1 = pk_fma_s1(L2, paz, pk_fma_s0(L2, pay, pk_mul_s1(L1, pax)));
        f2 t1 = pk_mul_s1(L10, m1);
        t1.x = __builtin_amdgcn_fmed3f(t1.x, 0.0f, 1.0f);
        t1.y = __builtin_amdgcn_fmed3f(t1.y, 0.0f, 1.0f);
        // d1 = pa - ba*t1 ; e1 = |d1|^2
        f2 d1x = pk_fma_s1(L1, t1, pax);
        f2 d1y = pk_fma_s0(L2, t1, pay);
        f2 d1z = pk_fma_s1(L2, t1, paz);
        f2 e1 = dot3_v(d1x, d1y, d1z);

        // pb = pa - ba
        f2 pbx = pk_add_s1(L1, pax);
        f2 pby = pk_add_s0(L2, pay);
        f2 pbz = pk_add_s1(L2, paz);

        // s2 = c2.pb
        f2 s2v = pk_fma_s1(L8, pbz, pk_fma_s0(L8, pby, pk_mul_s1(L7, pbx)));
        // m2 = -cb.pb ; t2
        f2 m2 = pk_fma_s0(L4, pbz, pk_fma_s1(L3, pby, pk_mul_s0(L3, pbx)));
        f2 t2 = pk_mul_s0(L11, m2);
        t2.x = __builtin_amdgcn_fmed3f(t2.x, 0.0f, 1.0f);
        t2.y = __builtin_amdgcn_fmed3f(t2.y, 0.0f, 1.0f);
        f2 d2x = pk_fma_s0(L3, t2, pbx);
        f2 d2y = pk_fma_s1(L3, t2, pby);
        f2 d2z = pk_fma_s0(L4, t2, pbz);
        f2 e2 = dot3_v(d2x, d2y, d2z);

        // pc = pb - cb
        f2 pcx = pk_add_s0(L3, pbx);
        f2 pcy = pk_add_s1(L3, pby);
        f2 pcz = pk_add_s0(L4, pbz);

        // m3 = -ac.pc ; t3
        f2 m3 = pk_fma_s1(L5, pcz, pk_fma_s0(L5, pcy, pk_mul_s1(L4, pcx)));
        f2 t3 = pk_mul_s1(L11, m3);
        t3.x = __builtin_amdgcn_fmed3f(t3.x, 0.0f, 1.0f);
        t3.y = __builtin_amdgcn_fmed3f(t3.y, 0.0f, 1.0f);
        f2 d3x = pk_fma_s1(L4, t3, pcx);
        f2 d3y = pk_fma_s0(L5, t3, pcy);
        f2 d3z = pk_fma_s1(L5, t3, pcz);
        f2 e3 = dot3_v(d3x, d3y, d3z);

        // plane distance
        f2 dn = pk_fma_s0(L10, paz, pk_fma_s1(L9, pay, pk_mul_s0(L9, pax)));
        f2 opp = pk_mul_s0(L12, pk_mul_vv(dn, dn));

        // s3 = nsq - s1 - s2  (exact identity: c1+c2+c3 = 0)
        f2 u = pk_add_vv(s1v, s2v);
        float nsqf = L12.y;                 // SGPR
        float s3x = nsqf - u.x;
        float s3y = nsqf - u.y;

        // inside <=> min3(s)>=0 AND med3(s)>0
        float mn0  = fminf(fminf(s1v.x, s2v.x), s3x);
        float mn1  = fminf(fminf(s1v.y, s2v.y), s3y);
        float med0 = __builtin_amdgcn_fmed3f(s1v.x, s2v.x, s3x);
        float med1 = __builtin_amdgcn_fmed3f(s1v.y, s2v.y, s3y);
        float same0 = fminf(fminf(e1.x, e2.x), e3.x);
        float same1 = fminf(fminf(e1.y, e2.y), e3.y);
        bool in0 = (med0 > 0.0f) & (mn0 >= 0.0f);
        bool in1 = (med1 > 0.0f) & (mn1 >= 0.0f);
        float q0 = in0 ? opp.x : same0;
        float q1 = in1 ? opp.y : same1;

        float dd0 = __builtin_amdgcn_sqrtf(fmaxf(q0, 1e-8f));
        float dd1 = __builtin_amdgcn_sqrtf(fmaxf(q1, 1e-8f));
        sum0 += __builtin_amdgcn_exp2f(fmaf(dd0, EK, EB));
        sum1 += __builtin_amdgcn_exp2f(fmaf(dd1, EK, EB));
    }

    red[chunk][lane]      = sum0;
    red[chunk][lane + 64] = sum1;
    __syncthreads();

    if (tid < 128) {
        float total = ((red[0][tid] + red[1][tid]) + (red[2][tid] + red[3][tid]))
                    + ((red[4][tid] + red[5][tid]) + (red[6][tid] + red[7][tid]));
        out[blockIdx.x * 128 + tid] =
            -__builtin_amdgcn_logf(fmaxf(total, 1e-6f)) * 0.02166084939249829f;
    }
}

extern "C" void kernel_launch(void* const* d_in, const int* in_sizes, int n_in,
                              void* d_out, int out_size, void* d_ws, size_t ws_size,
                              hipStream_t stream) {
    const float* p      = (const float*)d_in[0];
    const float* points = (const float*)d_in[1];
    float* out          = (float*)d_out;
    float* pre          = (float*)d_ws;          // 256 * 32 * 4 B = 32 KB

    hipLaunchKernelGGL(tri_pre_kernel, dim3(1), dim3(256), 0, stream, points, pre);

    const int n_pts = in_sizes[0] / 3;
    const int blocks = (n_pts + 127) / 128;      // 1024 for 131072 pts
    hipLaunchKernelGGL(tri_main_kernel, dim3(blocks), dim3(512), 0, stream,
                       p, pre, out);
}